// Round 2
// baseline (3299.906 us; speedup 1.0000x reference)
//
#include <hip/hip_runtime.h>
#include <hip/hip_bf16.h>
#include <cstdint>
#include <cstddef>

// Problem constants
#define B_SZ   256
#define T_SZ   2049
#define D_SZ   64
#define H_SZ   64
#define MLP_SZ 128
#define NI_SZ  128
#define SEG    16          // (T-1)/NI
#define L_SZ   2080        // D + D(D-1)/2
#define NPAIR  2016
#define OUT_SZ 10

// GEMM shapes
#define NC     16                  // intervals per chunk
#define NCHUNK (NI_SZ / NC)        // 8
#define MROWS  (NC * B_SZ)         // 4096 rows per chunk GEMM
#define NCOLS  8320                // 8192 (W2 rows m*64+d) + 64 (b2) + 64 zero pad -> 65*128
#define KDIM   L_SZ                // 2080 = 65*32

typedef _Float16 f16x8 __attribute__((ext_vector_type(8)));
typedef float    f32x4 __attribute__((ext_vector_type(4)));

// ---------------------------------------------------------------------------
// Build Bmat (fp16, [NCOLS x KDIM] row-major):
//   rows 0..8191   : W2 flat (W2[m][d*L+l] == flat r*K+l with r=m*64+d — identity)
//   rows 8192..8255: b2 reshaped [64 x 2080]
//   rows 8256..8319: zeros (pad to multiple of 128)
// ---------------------------------------------------------------------------
__global__ void build_B(const float* __restrict__ W2, const float* __restrict__ b2,
                        _Float16* __restrict__ Bm) {
    const size_t NW = (size_t)8192 * KDIM;          // W2 part
    const size_t NB = NW + (size_t)64 * KDIM;       // + b2 part
    const size_t NT = (size_t)NCOLS * KDIM;
    for (size_t i = (size_t)blockIdx.x * blockDim.x + threadIdx.x; i < NT;
         i += (size_t)gridDim.x * blockDim.x) {
        float v = (i < NW) ? W2[i] : ((i < NB) ? b2[i - NW] : 0.0f);
        Bm[i] = (_Float16)v;
    }
}

// ---------------------------------------------------------------------------
// h0 = X[:,0,:] @ W_in + b_in          <<<256, 64>>>
// ---------------------------------------------------------------------------
__global__ void h0_kernel(const float* __restrict__ X, const float* __restrict__ W_in,
                          const float* __restrict__ b_in, float* __restrict__ h_state) {
    const int b = blockIdx.x, t = threadIdx.x;
    __shared__ float x0[D_SZ];
    if (t < D_SZ) x0[t] = X[(size_t)b * T_SZ * D_SZ + t];
    __syncthreads();
    float acc = b_in[t];
    for (int k = 0; k < D_SZ; ++k) acc += x0[k] * W_in[k * H_SZ + t];
    h_state[b * H_SZ + t] = acc;
}

// ---------------------------------------------------------------------------
// Depth-2 log-signature for one chunk of NC intervals.
// LS layout: row r = sl*256 + b (sl = local interval), K-contiguous, fp16.
// grid (256, NC), 256 threads.
// ---------------------------------------------------------------------------
__global__ __launch_bounds__(256) void logsig_kernel(const float* __restrict__ X,
                                                     _Float16* __restrict__ LS,
                                                     int n0) {
    const int b = blockIdx.x, sl = blockIdx.y, t = threadIdx.x;
    const int n = n0 + sl;
    __shared__ float seg[SEG + 1][D_SZ];
    __shared__ float cum[SEG][D_SZ];
    __shared__ float dlt[SEG][D_SZ];

    const float* Xp = X + ((size_t)b * T_SZ + (size_t)n * SEG) * D_SZ;
    for (int i = t; i < (SEG + 1) * D_SZ; i += 256) seg[i / D_SZ][i % D_SZ] = Xp[i];
    __syncthreads();
    for (int i = t; i < SEG * D_SZ; i += 256) {
        int k = i / D_SZ, d = i % D_SZ;
        float s0 = seg[0][d];
        cum[k][d] = seg[k][d] - s0;
        dlt[k][d] = seg[k + 1][d] - seg[k][d];
    }
    __syncthreads();

    _Float16* out = LS + (size_t)(sl * B_SZ + b) * KDIM;
    if (t < D_SZ) out[t] = (_Float16)(seg[SEG][t] - seg[0][t]);  // level-1 inc
    for (int p = t; p < NPAIR; p += 256) {
        int i = 0, rem = p;                     // decode (i,j), row-major triu order
        while (rem >= 63 - i) { rem -= 63 - i; ++i; }
        int j = i + 1 + rem;
        float a = 0.0f;
#pragma unroll
        for (int k = 0; k < SEG; ++k)
            a += cum[k][i] * dlt[k][j] - cum[k][j] * dlt[k][i];
        out[D_SZ + p] = (_Float16)(0.5f * a);
    }
}

// ---------------------------------------------------------------------------
// GEMM (m97 structure): C[M,N] fp32 = A[M,K] fp16 x B[N,K]^T fp16.
// 128x128 tile / block of 256 threads; BK=32; global_load_lds 16B staging;
// 4 waves each compute 64x64 via 4x4 frags of mfma_f32_16x16x32_f16.
// M=4096, N=8320, K=2080 all divisible -> no bounds checks.
// ---------------------------------------------------------------------------
__global__ __launch_bounds__(256) void gemm_bt(const unsigned short* __restrict__ A,
                                               const unsigned short* __restrict__ Bm,
                                               float* __restrict__ C) {
    constexpr int K = KDIM, N = NCOLS;
    __shared__ unsigned short As[128 * 32];
    __shared__ unsigned short Bs[128 * 32];
    const int t = threadIdx.x;
    const int lane = t & 63;
    const int w = t >> 6;
    const int wm = w & 1, wn = w >> 1;
    const int tileM = blockIdx.x * 128;
    const int tileN = blockIdx.y * 128;

    // staging: 8 chunks of 512 fp16 (16 rows x 32 k); wave w handles chunks 2w, 2w+1
    const int c0 = w * 2, c1 = c0 + 1;
    const int rs0 = c0 * 16 + (lane >> 2);
    const int rs1 = c1 * 16 + (lane >> 2);
    const int kc = (lane & 3) * 8;

    const unsigned short* gA0 = A + (size_t)(tileM + rs0) * K + kc;
    const unsigned short* gA1 = A + (size_t)(tileM + rs1) * K + kc;
    const unsigned short* gB0 = Bm + (size_t)(tileN + rs0) * K + kc;
    const unsigned short* gB1 = Bm + (size_t)(tileN + rs1) * K + kc;
    unsigned short* lA0 = As + c0 * 512 + lane * 8;
    unsigned short* lA1 = As + c1 * 512 + lane * 8;
    unsigned short* lB0 = Bs + c0 * 512 + lane * 8;
    unsigned short* lB1 = Bs + c1 * 512 + lane * 8;

    f32x4 acc[4][4] = {};
    const int frow = lane & 15;
    const int fk = (lane >> 4) * 8;

    for (int k0 = 0; k0 < K; k0 += 32) {
        __syncthreads();
        __builtin_amdgcn_global_load_lds((__attribute__((address_space(1))) void*)(gA0 + k0),
                                         (__attribute__((address_space(3))) void*)lA0, 16, 0, 0);
        __builtin_amdgcn_global_load_lds((__attribute__((address_space(1))) void*)(gA1 + k0),
                                         (__attribute__((address_space(3))) void*)lA1, 16, 0, 0);
        __builtin_amdgcn_global_load_lds((__attribute__((address_space(1))) void*)(gB0 + k0),
                                         (__attribute__((address_space(3))) void*)lB0, 16, 0, 0);
        __builtin_amdgcn_global_load_lds((__attribute__((address_space(1))) void*)(gB1 + k0),
                                         (__attribute__((address_space(3))) void*)lB1, 16, 0, 0);
        __syncthreads();

        f16x8 af[4], bfm[4];
#pragma unroll
        for (int mi = 0; mi < 4; ++mi)
            af[mi] = *(const f16x8*)(As + (wm * 64 + mi * 16 + frow) * 32 + fk);
#pragma unroll
        for (int ni = 0; ni < 4; ++ni)
            bfm[ni] = *(const f16x8*)(Bs + (wn * 64 + ni * 16 + frow) * 32 + fk);
#pragma unroll
        for (int mi = 0; mi < 4; ++mi)
#pragma unroll
            for (int ni = 0; ni < 4; ++ni)
                acc[mi][ni] = __builtin_amdgcn_mfma_f32_16x16x32_f16(af[mi], bfm[ni],
                                                                     acc[mi][ni], 0, 0, 0);
    }

    // C/D layout: col = lane&15, row = (lane>>4)*4 + reg   [m89-verified, dtype-indep]
    const int erow = (lane >> 4) * 4;
#pragma unroll
    for (int mi = 0; mi < 4; ++mi)
#pragma unroll
        for (int ni = 0; ni < 4; ++ni) {
            const int col = tileN + wn * 64 + ni * 16 + frow;
            const size_t rbase = (size_t)(tileM + wm * 64 + mi * 16 + erow) * N + col;
#pragma unroll
            for (int r = 0; r < 4; ++r)
                C[rbase + (size_t)r * N] = acc[mi][ni][r];
        }
}

// ---------------------------------------------------------------------------
// RK4 scan over NC intervals for one chunk. One block per batch element.
// G row (s*256+b): [m*64+d] for m<128, then [8192+d] = b2 contribution.
// ---------------------------------------------------------------------------
__global__ __launch_bounds__(256) void ode_chunk(const float* __restrict__ G,
                                                 const float* __restrict__ W1,
                                                 const float* __restrict__ b1,
                                                 float* __restrict__ h_state) {
    const int b = blockIdx.x, t = threadIdx.x;
    __shared__ float Gs[NCOLS];          // 33.3 KB
    __shared__ float b1s[MLP_SZ];
    __shared__ float hs[D_SZ], ys[D_SZ], zs[MLP_SZ];
    __shared__ float ks[4][D_SZ], part[4][D_SZ];

    if (t < MLP_SZ) b1s[t] = b1[t];
    if (t < D_SZ) hs[t] = h_state[b * H_SZ + t];
    __syncthreads();

    for (int s = 0; s < NC; ++s) {
        const float4* Grow = (const float4*)(G + (size_t)(s * B_SZ + b) * NCOLS);
        for (int i = t; i < NCOLS / 4; i += 256) ((float4*)Gs)[i] = Grow[i];
        __syncthreads();

        for (int st = 0; st < 4; ++st) {
            if (t < D_SZ) {
                float y = hs[t];
                if (st == 1) y += 0.5f * ks[0][t];
                else if (st == 2) y += 0.5f * ks[1][t];
                else if (st == 3) y += ks[2][t];
                ys[t] = y;
            }
            __syncthreads();
            if (t < MLP_SZ) {
                float acc = b1s[t];
#pragma unroll
                for (int d = 0; d < D_SZ; ++d) acc += ys[d] * W1[d * MLP_SZ + t];
                zs[t] = tanhf(acc);
            }
            __syncthreads();
            {
                const int d = t & 63, mh = t >> 6;
                float acc = 0.0f;
#pragma unroll
                for (int m = 0; m < 32; ++m) acc += zs[mh * 32 + m] * Gs[(mh * 32 + m) * 64 + d];
                part[mh][d] = acc;
            }
            __syncthreads();
            if (t < D_SZ)
                ks[st][t] = Gs[8192 + t] + part[0][t] + part[1][t] + part[2][t] + part[3][t];
            __syncthreads();
        }
        if (t < D_SZ)
            hs[t] += (ks[0][t] + 2.0f * ks[1][t] + 2.0f * ks[2][t] + ks[3][t]) * (1.0f / 6.0f);
        __syncthreads();
    }
    if (t < D_SZ) h_state[b * H_SZ + t] = hs[t];
}

// ---------------------------------------------------------------------------
// out = hT @ W_out + b_out             <<<256, 64>>>
// ---------------------------------------------------------------------------
__global__ void out_kernel(const float* __restrict__ h_state, const float* __restrict__ W_out,
                           const float* __restrict__ b_out, float* __restrict__ out) {
    const int b = blockIdx.x, t = threadIdx.x;
    __shared__ float hh[H_SZ];
    hh[t] = h_state[b * H_SZ + t];
    __syncthreads();
    if (t < OUT_SZ) {
        float acc = b_out[t];
        for (int d = 0; d < H_SZ; ++d) acc += hh[d] * W_out[d * OUT_SZ + t];
        out[b * OUT_SZ + t] = acc;
    }
}

extern "C" void kernel_launch(void* const* d_in, const int* in_sizes, int n_in,
                              void* d_out, int out_size, void* d_ws, size_t ws_size,
                              hipStream_t stream) {
    (void)in_sizes; (void)n_in; (void)out_size; (void)ws_size;
    const float* X     = (const float*)d_in[0];
    const float* W_in  = (const float*)d_in[1];
    const float* b_in  = (const float*)d_in[2];
    const float* W1    = (const float*)d_in[3];
    const float* b1    = (const float*)d_in[4];
    const float* W2    = (const float*)d_in[5];
    const float* b2    = (const float*)d_in[6];
    const float* W_out = (const float*)d_in[7];
    const float* b_out = (const float*)d_in[8];
    float* out = (float*)d_out;

    // workspace layout (~188 MB total)
    char* ws = (char*)d_ws;
    size_t off = 0;
    auto take = [&](size_t bytes) { void* p = ws + off; off = (off + bytes + 255) & ~(size_t)255; return p; };
    _Float16* Bmat = (_Float16*)take((size_t)NCOLS * KDIM * 2);   // 34.6 MB
    _Float16* LSc  = (_Float16*)take((size_t)MROWS * KDIM * 2);   // 17.0 MB
    float*    G    = (float*)take((size_t)MROWS * NCOLS * 4);     // 136.3 MB
    float*    hst  = (float*)take((size_t)B_SZ * H_SZ * 4);       // 64 KB

    build_B<<<8192, 256, 0, stream>>>(W2, b2, Bmat);
    h0_kernel<<<B_SZ, H_SZ, 0, stream>>>(X, W_in, b_in, hst);

    for (int c = 0; c < NCHUNK; ++c) {
        logsig_kernel<<<dim3(B_SZ, NC), 256, 0, stream>>>(X, LSc, c * NC);
        gemm_bt<<<dim3(MROWS / 128, NCOLS / 128), 256, 0, stream>>>(
            (const unsigned short*)LSc, (const unsigned short*)Bmat, G);
        ode_chunk<<<B_SZ, 256, 0, stream>>>(G, W1, b1, hst);
    }
    out_kernel<<<B_SZ, H_SZ, 0, stream>>>(hst, W_out, b_out, out);
}

// Round 3
// 2377.283 us; speedup vs baseline: 1.3881x; 1.3881x over previous
//
#include <hip/hip_runtime.h>
#include <hip/hip_bf16.h>
#include <cstdint>
#include <cstddef>

// Problem constants
#define B_SZ   256
#define T_SZ   2049
#define D_SZ   64
#define H_SZ   64
#define MLP_SZ 128
#define NI_SZ  128
#define SEG    16          // (T-1)/NI
#define L_SZ   2080        // D + D(D-1)/2
#define NPAIR  2016
#define OUT_SZ 10

// GEMM shapes
#define NC     16                  // intervals per chunk
#define NCHUNK (NI_SZ / NC)        // 8
#define MROWS  (NC * B_SZ)         // 4096 rows per chunk GEMM
#define NCOLS  8320                // 8192 (W2 rows m*64+d) + 64 (b2) + 64 zero pad
#define KDIM   L_SZ                // 2080 = 65*32

typedef _Float16 f16x8 __attribute__((ext_vector_type(8)));
typedef float    f32x4 __attribute__((ext_vector_type(4)));

// ---------------------------------------------------------------------------
// Build Bmat (fp16, [NCOLS x KDIM] row-major): W2 rows, b2 rows, zero pad.
// ---------------------------------------------------------------------------
__global__ void build_B(const float* __restrict__ W2, const float* __restrict__ b2,
                        _Float16* __restrict__ Bm) {
    const size_t NW = (size_t)8192 * KDIM;
    const size_t NB = NW + (size_t)64 * KDIM;
    const size_t NT = (size_t)NCOLS * KDIM;
    for (size_t i = (size_t)blockIdx.x * blockDim.x + threadIdx.x; i < NT;
         i += (size_t)gridDim.x * blockDim.x) {
        float v = (i < NW) ? W2[i] : ((i < NB) ? b2[i - NW] : 0.0f);
        Bm[i] = (_Float16)v;
    }
}

// ---------------------------------------------------------------------------
// h0 = X[:,0,:] @ W_in + b_in          <<<256, 64>>>
// ---------------------------------------------------------------------------
__global__ void h0_kernel(const float* __restrict__ X, const float* __restrict__ W_in,
                          const float* __restrict__ b_in, float* __restrict__ h_state) {
    const int b = blockIdx.x, t = threadIdx.x;
    __shared__ float x0[D_SZ];
    if (t < D_SZ) x0[t] = X[(size_t)b * T_SZ * D_SZ + t];
    __syncthreads();
    float acc = b_in[t];
    for (int k = 0; k < D_SZ; ++k) acc += x0[k] * W_in[k * H_SZ + t];
    h_state[b * H_SZ + t] = acc;
}

// ---------------------------------------------------------------------------
// Depth-2 log-signature, tile-structured:
//   phase 1: full M = cum^T @ dlt via 4x4 register tiles (2 ds_read_b128/k)
//   phase 2: closed-form Lyndon index, A = 0.5(M - M^T) upper triangle
// grid (256, NC), 256 threads. LDS ~28.5 KB.
// ---------------------------------------------------------------------------
__global__ __launch_bounds__(256) void logsig_kernel(const float* __restrict__ X,
                                                     _Float16* __restrict__ LS,
                                                     int n0) {
    const int b = blockIdx.x, sl = blockIdx.y, t = threadIdx.x;
    const int n = n0 + sl;
    __shared__ float seg[SEG + 1][D_SZ];
    __shared__ float cum[SEG][D_SZ];
    __shared__ float dlt[SEG][D_SZ];
    __shared__ float Mm[D_SZ][D_SZ + 1];   // +1 pad: transpose reads conflict-free

    const float* Xp = X + ((size_t)b * T_SZ + (size_t)n * SEG) * D_SZ;
    for (int i = t; i < (SEG + 1) * D_SZ / 4; i += 256)
        ((float4*)&seg[0][0])[i] = ((const float4*)Xp)[i];
    __syncthreads();
    for (int i = t; i < SEG * D_SZ; i += 256) {
        const int k = i >> 6, d = i & 63;
        cum[k][d] = seg[k][d] - seg[0][d];
        dlt[k][d] = seg[k + 1][d] - seg[k][d];
    }
    __syncthreads();

    const int ti = t >> 4, tj = t & 15;
    const int i0 = ti * 4, j0 = tj * 4;
    float m4[4][4] = {};
#pragma unroll
    for (int k = 0; k < SEG; ++k) {
        const float4 ci = *(const float4*)&cum[k][i0];
        const float4 dj = *(const float4*)&dlt[k][j0];
        const float* cip = (const float*)&ci;
        const float* djp = (const float*)&dj;
#pragma unroll
        for (int a = 0; a < 4; ++a)
#pragma unroll
            for (int c = 0; c < 4; ++c)
                m4[a][c] += cip[a] * djp[c];
    }
#pragma unroll
    for (int a = 0; a < 4; ++a)
#pragma unroll
        for (int c = 0; c < 4; ++c)
            Mm[i0 + a][j0 + c] = m4[a][c];
    __syncthreads();

    _Float16* out = LS + (size_t)(sl * B_SZ + b) * KDIM;
    if (t < D_SZ) out[t] = (_Float16)(seg[SEG][t] - seg[0][t]);   // level-1 inc
    if (tj >= ti) {
#pragma unroll
        for (int a = 0; a < 4; ++a) {
            const int i = i0 + a;
#pragma unroll
            for (int c = 0; c < 4; ++c) {
                const int j = j0 + c;
                if (j > i) {
                    const int p = 63 * i - (i * (i - 1)) / 2 + (j - i - 1);
                    out[D_SZ + p] = (_Float16)(0.5f * (m4[a][c] - Mm[j][i]));
                }
            }
        }
    }
}

// ---------------------------------------------------------------------------
// GEMM (m97 structure): C[M,N] fp16 = A[M,K] fp16 x B[N,K]^T fp16.
// 128x128 tile; BK=32; global_load_lds 16B staging; mfma_f32_16x16x32_f16.
// ---------------------------------------------------------------------------
__global__ __launch_bounds__(256) void gemm_bt(const unsigned short* __restrict__ A,
                                               const unsigned short* __restrict__ Bm,
                                               _Float16* __restrict__ C) {
    constexpr int K = KDIM, N = NCOLS;
    __shared__ unsigned short As[128 * 32];
    __shared__ unsigned short Bs[128 * 32];
    const int t = threadIdx.x;
    const int lane = t & 63;
    const int w = t >> 6;
    const int wm = w & 1, wn = w >> 1;
    const int tileM = blockIdx.x * 128;
    const int tileN = blockIdx.y * 128;

    const int c0 = w * 2, c1 = c0 + 1;
    const int rs0 = c0 * 16 + (lane >> 2);
    const int rs1 = c1 * 16 + (lane >> 2);
    const int kc = (lane & 3) * 8;

    const unsigned short* gA0 = A + (size_t)(tileM + rs0) * K + kc;
    const unsigned short* gA1 = A + (size_t)(tileM + rs1) * K + kc;
    const unsigned short* gB0 = Bm + (size_t)(tileN + rs0) * K + kc;
    const unsigned short* gB1 = Bm + (size_t)(tileN + rs1) * K + kc;
    unsigned short* lA0 = As + c0 * 512 + lane * 8;
    unsigned short* lA1 = As + c1 * 512 + lane * 8;
    unsigned short* lB0 = Bs + c0 * 512 + lane * 8;
    unsigned short* lB1 = Bs + c1 * 512 + lane * 8;

    f32x4 acc[4][4] = {};
    const int frow = lane & 15;
    const int fk = (lane >> 4) * 8;

    for (int k0 = 0; k0 < K; k0 += 32) {
        __syncthreads();
        __builtin_amdgcn_global_load_lds((__attribute__((address_space(1))) void*)(gA0 + k0),
                                         (__attribute__((address_space(3))) void*)lA0, 16, 0, 0);
        __builtin_amdgcn_global_load_lds((__attribute__((address_space(1))) void*)(gA1 + k0),
                                         (__attribute__((address_space(3))) void*)lA1, 16, 0, 0);
        __builtin_amdgcn_global_load_lds((__attribute__((address_space(1))) void*)(gB0 + k0),
                                         (__attribute__((address_space(3))) void*)lB0, 16, 0, 0);
        __builtin_amdgcn_global_load_lds((__attribute__((address_space(1))) void*)(gB1 + k0),
                                         (__attribute__((address_space(3))) void*)lB1, 16, 0, 0);
        __syncthreads();

        f16x8 af[4], bfm[4];
#pragma unroll
        for (int mi = 0; mi < 4; ++mi)
            af[mi] = *(const f16x8*)(As + (wm * 64 + mi * 16 + frow) * 32 + fk);
#pragma unroll
        for (int ni = 0; ni < 4; ++ni)
            bfm[ni] = *(const f16x8*)(Bs + (wn * 64 + ni * 16 + frow) * 32 + fk);
#pragma unroll
        for (int mi = 0; mi < 4; ++mi)
#pragma unroll
            for (int ni = 0; ni < 4; ++ni)
                acc[mi][ni] = __builtin_amdgcn_mfma_f32_16x16x32_f16(af[mi], bfm[ni],
                                                                     acc[mi][ni], 0, 0, 0);
    }

    // C/D layout: col = lane&15, row = (lane>>4)*4 + reg
    const int erow = (lane >> 4) * 4;
#pragma unroll
    for (int mi = 0; mi < 4; ++mi)
#pragma unroll
        for (int ni = 0; ni < 4; ++ni) {
            const int col = tileN + wn * 64 + ni * 16 + frow;
            const size_t rbase = (size_t)(tileM + wm * 64 + mi * 16 + erow) * N + col;
#pragma unroll
            for (int r = 0; r < 4; ++r)
                C[rbase + (size_t)r * N] = (_Float16)acc[mi][ni][r];
        }
}

// ---------------------------------------------------------------------------
// RK4 scan, register-resident G with cross-step prefetch. One block per batch.
// Thread (mh = t>>6, d = t&63) holds G[(mh*32+m)*64+d] m=0..31 in registers.
// W1 column in registers (t<128). k_st / h in wave-0 registers.
// ---------------------------------------------------------------------------
__global__ __launch_bounds__(256) void ode_chunk(const _Float16* __restrict__ G,
                                                 const float* __restrict__ W1,
                                                 const float* __restrict__ b1,
                                                 float* __restrict__ h_state) {
    const int b = blockIdx.x, t = threadIdx.x;
    const int d = t & 63, mh = t >> 6;
    __shared__ float ys[D_SZ];
    __shared__ float zs[MLP_SZ];
    __shared__ float part[4][D_SZ];

    float w1c[D_SZ];                       // W1[:,t] for t<128 (64 VGPRs; 1 block/CU)
    if (t < MLP_SZ) {
#pragma unroll
        for (int dd = 0; dd < D_SZ; ++dd) w1c[dd] = W1[dd * MLP_SZ + t];
    }
    const float b1v = (t < MLP_SZ) ? b1[t] : 0.0f;
    float hsv = (t < D_SZ) ? h_state[b * H_SZ + t] : 0.0f;

    _Float16 praw[32];
    _Float16 b2pre;
    {
        const _Float16* Gr = G + (size_t)b * NCOLS;   // s = 0
#pragma unroll
        for (int m = 0; m < 32; ++m) praw[m] = Gr[(mh * 32 + m) * 64 + d];
        b2pre = Gr[8192 + d];
    }

    float k_st[4] = {0.f, 0.f, 0.f, 0.f};
#pragma unroll 1
    for (int s = 0; s < NC; ++s) {
        float gcur[32];
#pragma unroll
        for (int m = 0; m < 32; ++m) gcur[m] = (float)praw[m];
        const float b2cur = (float)b2pre;
        if (s + 1 < NC) {                  // prefetch next step's row (hidden by stages)
            const _Float16* Gr = G + (size_t)((s + 1) * B_SZ + b) * NCOLS;
#pragma unroll
            for (int m = 0; m < 32; ++m) praw[m] = Gr[(mh * 32 + m) * 64 + d];
            b2pre = Gr[8192 + d];
        }

#pragma unroll
        for (int st = 0; st < 4; ++st) {
            if (t < D_SZ) {
                float y = hsv;
                if (st == 1) y += 0.5f * k_st[0];
                else if (st == 2) y += 0.5f * k_st[1];
                else if (st == 3) y += k_st[2];
                ys[t] = y;
            }
            __syncthreads();
            if (t < MLP_SZ) {
                float a0 = 0.f, a1 = 0.f, a2 = 0.f, a3 = 0.f;
#pragma unroll
                for (int dd = 0; dd < D_SZ; dd += 4) {
                    a0 += ys[dd + 0] * w1c[dd + 0];
                    a1 += ys[dd + 1] * w1c[dd + 1];
                    a2 += ys[dd + 2] * w1c[dd + 2];
                    a3 += ys[dd + 3] * w1c[dd + 3];
                }
                const float x = b1v + ((a0 + a1) + (a2 + a3));
                const float ex = __expf(2.0f * x);      // tanh(x)=1-2/(e^{2x}+1)
                zs[t] = 1.0f - 2.0f / (ex + 1.0f);
            }
            __syncthreads();
            {
                float a = 0.0f;
#pragma unroll
                for (int m = 0; m < 32; ++m) a += gcur[m] * zs[mh * 32 + m];
                part[mh][d] = a;
            }
            __syncthreads();
            if (t < D_SZ)
                k_st[st] = b2cur + part[0][d] + part[1][d] + part[2][d] + part[3][d];
        }
        if (t < D_SZ)
            hsv += (k_st[0] + 2.0f * k_st[1] + 2.0f * k_st[2] + k_st[3]) * (1.0f / 6.0f);
    }
    if (t < D_SZ) h_state[b * H_SZ + t] = hsv;
}

// ---------------------------------------------------------------------------
// out = hT @ W_out + b_out             <<<256, 64>>>
// ---------------------------------------------------------------------------
__global__ void out_kernel(const float* __restrict__ h_state, const float* __restrict__ W_out,
                           const float* __restrict__ b_out, float* __restrict__ out) {
    const int b = blockIdx.x, t = threadIdx.x;
    __shared__ float hh[H_SZ];
    hh[t] = h_state[b * H_SZ + t];
    __syncthreads();
    if (t < OUT_SZ) {
        float acc = b_out[t];
        for (int d = 0; d < H_SZ; ++d) acc += hh[d] * W_out[d * OUT_SZ + t];
        out[b * OUT_SZ + t] = acc;
    }
}

extern "C" void kernel_launch(void* const* d_in, const int* in_sizes, int n_in,
                              void* d_out, int out_size, void* d_ws, size_t ws_size,
                              hipStream_t stream) {
    (void)in_sizes; (void)n_in; (void)out_size; (void)ws_size;
    const float* X     = (const float*)d_in[0];
    const float* W_in  = (const float*)d_in[1];
    const float* b_in  = (const float*)d_in[2];
    const float* W1    = (const float*)d_in[3];
    const float* b1    = (const float*)d_in[4];
    const float* W2    = (const float*)d_in[5];
    const float* b2    = (const float*)d_in[6];
    const float* W_out = (const float*)d_in[7];
    const float* b_out = (const float*)d_in[8];
    float* out = (float*)d_out;

    // workspace layout (~120 MB total)
    char* ws = (char*)d_ws;
    size_t off = 0;
    auto take = [&](size_t bytes) { void* p = ws + off; off = (off + bytes + 255) & ~(size_t)255; return p; };
    _Float16* Bmat = (_Float16*)take((size_t)NCOLS * KDIM * 2);   // 34.6 MB
    _Float16* LSc  = (_Float16*)take((size_t)MROWS * KDIM * 2);   // 17.0 MB
    _Float16* G    = (_Float16*)take((size_t)MROWS * NCOLS * 2);  // 68.1 MB
    float*    hst  = (float*)take((size_t)B_SZ * H_SZ * 4);       // 64 KB

    build_B<<<8192, 256, 0, stream>>>(W2, b2, Bmat);
    h0_kernel<<<B_SZ, H_SZ, 0, stream>>>(X, W_in, b_in, hst);

    for (int c = 0; c < NCHUNK; ++c) {
        logsig_kernel<<<dim3(B_SZ, NC), 256, 0, stream>>>(X, LSc, c * NC);
        gemm_bt<<<dim3(MROWS / 128, NCOLS / 128), 256, 0, stream>>>(
            (const unsigned short*)LSc, (const unsigned short*)Bmat, G);
        ode_chunk<<<B_SZ, 256, 0, stream>>>(G, W1, b1, hst);
    }
    out_kernel<<<B_SZ, H_SZ, 0, stream>>>(hst, W_out, b_out, out);
}

// Round 4
// 2372.747 us; speedup vs baseline: 1.3908x; 1.0019x over previous
//
#include <hip/hip_runtime.h>
#include <hip/hip_bf16.h>
#include <cstdint>
#include <cstddef>

// Problem constants
#define B_SZ   256
#define T_SZ   2049
#define D_SZ   64
#define H_SZ   64
#define MLP_SZ 128
#define NI_SZ  128
#define SEG    16          // (T-1)/NI
#define L_SZ   2080        // D + D(D-1)/2
#define NPAIR  2016
#define OUT_SZ 10

// GEMM shapes
#define NC     16                  // intervals per chunk
#define NCHUNK (NI_SZ / NC)        // 8
#define MROWS  (NC * B_SZ)         // 4096 rows per chunk GEMM
#define NCOLS  8320                // 8192 (W2 rows m*64+d) + 64 (b2) + 64 zero pad
#define KDIM   L_SZ                // 2080 = 65*32

typedef _Float16 f16x8 __attribute__((ext_vector_type(8)));
typedef float    f32x4 __attribute__((ext_vector_type(4)));

__device__ __forceinline__ float rlane(float v, int l) {
    return __uint_as_float(__builtin_amdgcn_readlane(__float_as_uint(v), l));
}

// ---------------------------------------------------------------------------
// Build Bmat (fp16, [NCOLS x KDIM] row-major): W2 rows, b2 rows, zero pad.
// ---------------------------------------------------------------------------
__global__ void build_B(const float* __restrict__ W2, const float* __restrict__ b2,
                        _Float16* __restrict__ Bm) {
    const size_t NW = (size_t)8192 * KDIM;
    const size_t NB = NW + (size_t)64 * KDIM;
    const size_t NT = (size_t)NCOLS * KDIM;
    for (size_t i = (size_t)blockIdx.x * blockDim.x + threadIdx.x; i < NT;
         i += (size_t)gridDim.x * blockDim.x) {
        float v = (i < NW) ? W2[i] : ((i < NB) ? b2[i - NW] : 0.0f);
        Bm[i] = (_Float16)v;
    }
}

// ---------------------------------------------------------------------------
// h0 = X[:,0,:] @ W_in + b_in          <<<256, 64>>>
// ---------------------------------------------------------------------------
__global__ void h0_kernel(const float* __restrict__ X, const float* __restrict__ W_in,
                          const float* __restrict__ b_in, float* __restrict__ h_state) {
    const int b = blockIdx.x, t = threadIdx.x;
    __shared__ float x0[D_SZ];
    if (t < D_SZ) x0[t] = X[(size_t)b * T_SZ * D_SZ + t];
    __syncthreads();
    float acc = b_in[t];
    for (int k = 0; k < D_SZ; ++k) acc += x0[k] * W_in[k * H_SZ + t];
    h_state[b * H_SZ + t] = acc;
}

// ---------------------------------------------------------------------------
// Depth-2 log-signature, tile-structured (4x4 register tiles, Lyndon order).
// grid (256, NC), 256 threads.
// ---------------------------------------------------------------------------
__global__ __launch_bounds__(256) void logsig_kernel(const float* __restrict__ X,
                                                     _Float16* __restrict__ LS,
                                                     int n0) {
    const int b = blockIdx.x, sl = blockIdx.y, t = threadIdx.x;
    const int n = n0 + sl;
    __shared__ float seg[SEG + 1][D_SZ];
    __shared__ float cum[SEG][D_SZ];
    __shared__ float dlt[SEG][D_SZ];
    __shared__ float Mm[D_SZ][D_SZ + 1];   // +1 pad: transpose reads conflict-free

    const float* Xp = X + ((size_t)b * T_SZ + (size_t)n * SEG) * D_SZ;
    for (int i = t; i < (SEG + 1) * D_SZ / 4; i += 256)
        ((float4*)&seg[0][0])[i] = ((const float4*)Xp)[i];
    __syncthreads();
    for (int i = t; i < SEG * D_SZ; i += 256) {
        const int k = i >> 6, d = i & 63;
        cum[k][d] = seg[k][d] - seg[0][d];
        dlt[k][d] = seg[k + 1][d] - seg[k][d];
    }
    __syncthreads();

    const int ti = t >> 4, tj = t & 15;
    const int i0 = ti * 4, j0 = tj * 4;
    float m4[4][4] = {};
#pragma unroll
    for (int k = 0; k < SEG; ++k) {
        const float4 ci = *(const float4*)&cum[k][i0];
        const float4 dj = *(const float4*)&dlt[k][j0];
        const float* cip = (const float*)&ci;
        const float* djp = (const float*)&dj;
#pragma unroll
        for (int a = 0; a < 4; ++a)
#pragma unroll
            for (int c = 0; c < 4; ++c)
                m4[a][c] += cip[a] * djp[c];
    }
#pragma unroll
    for (int a = 0; a < 4; ++a)
#pragma unroll
        for (int c = 0; c < 4; ++c)
            Mm[i0 + a][j0 + c] = m4[a][c];
    __syncthreads();

    _Float16* out = LS + (size_t)(sl * B_SZ + b) * KDIM;
    if (t < D_SZ) out[t] = (_Float16)(seg[SEG][t] - seg[0][t]);   // level-1 inc
    if (tj >= ti) {
#pragma unroll
        for (int a = 0; a < 4; ++a) {
            const int i = i0 + a;
#pragma unroll
            for (int c = 0; c < 4; ++c) {
                const int j = j0 + c;
                if (j > i) {
                    const int p = 63 * i - (i * (i - 1)) / 2 + (j - i - 1);
                    out[D_SZ + p] = (_Float16)(0.5f * (m4[a][c] - Mm[j][i]));
                }
            }
        }
    }
}

// ---------------------------------------------------------------------------
// GEMM (m97 structure): C[M,N] fp16 = A[M,K] fp16 x B[N,K]^T fp16.
// 128x128 tile; BK=32; global_load_lds 16B staging; mfma_f32_16x16x32_f16.
// ---------------------------------------------------------------------------
__global__ __launch_bounds__(256) void gemm_bt(const unsigned short* __restrict__ A,
                                               const unsigned short* __restrict__ Bm,
                                               _Float16* __restrict__ C) {
    constexpr int K = KDIM, N = NCOLS;
    __shared__ unsigned short As[128 * 32];
    __shared__ unsigned short Bs[128 * 32];
    const int t = threadIdx.x;
    const int lane = t & 63;
    const int w = t >> 6;
    const int wm = w & 1, wn = w >> 1;
    const int tileM = blockIdx.x * 128;
    const int tileN = blockIdx.y * 128;

    const int c0 = w * 2, c1 = c0 + 1;
    const int rs0 = c0 * 16 + (lane >> 2);
    const int rs1 = c1 * 16 + (lane >> 2);
    const int kc = (lane & 3) * 8;

    const unsigned short* gA0 = A + (size_t)(tileM + rs0) * K + kc;
    const unsigned short* gA1 = A + (size_t)(tileM + rs1) * K + kc;
    const unsigned short* gB0 = Bm + (size_t)(tileN + rs0) * K + kc;
    const unsigned short* gB1 = Bm + (size_t)(tileN + rs1) * K + kc;
    unsigned short* lA0 = As + c0 * 512 + lane * 8;
    unsigned short* lA1 = As + c1 * 512 + lane * 8;
    unsigned short* lB0 = Bs + c0 * 512 + lane * 8;
    unsigned short* lB1 = Bs + c1 * 512 + lane * 8;

    f32x4 acc[4][4] = {};
    const int frow = lane & 15;
    const int fk = (lane >> 4) * 8;

    for (int k0 = 0; k0 < K; k0 += 32) {
        __syncthreads();
        __builtin_amdgcn_global_load_lds((__attribute__((address_space(1))) void*)(gA0 + k0),
                                         (__attribute__((address_space(3))) void*)lA0, 16, 0, 0);
        __builtin_amdgcn_global_load_lds((__attribute__((address_space(1))) void*)(gA1 + k0),
                                         (__attribute__((address_space(3))) void*)lA1, 16, 0, 0);
        __builtin_amdgcn_global_load_lds((__attribute__((address_space(1))) void*)(gB0 + k0),
                                         (__attribute__((address_space(3))) void*)lB0, 16, 0, 0);
        __builtin_amdgcn_global_load_lds((__attribute__((address_space(1))) void*)(gB1 + k0),
                                         (__attribute__((address_space(3))) void*)lB1, 16, 0, 0);
        __syncthreads();

        f16x8 af[4], bfm[4];
#pragma unroll
        for (int mi = 0; mi < 4; ++mi)
            af[mi] = *(const f16x8*)(As + (wm * 64 + mi * 16 + frow) * 32 + fk);
#pragma unroll
        for (int ni = 0; ni < 4; ++ni)
            bfm[ni] = *(const f16x8*)(Bs + (wn * 64 + ni * 16 + frow) * 32 + fk);
#pragma unroll
        for (int mi = 0; mi < 4; ++mi)
#pragma unroll
            for (int ni = 0; ni < 4; ++ni)
                acc[mi][ni] = __builtin_amdgcn_mfma_f32_16x16x32_f16(af[mi], bfm[ni],
                                                                     acc[mi][ni], 0, 0, 0);
    }

    // C/D layout: col = lane&15, row = (lane>>4)*4 + reg
    const int erow = (lane >> 4) * 4;
#pragma unroll
    for (int mi = 0; mi < 4; ++mi)
#pragma unroll
        for (int ni = 0; ni < 4; ++ni) {
            const int col = tileN + wn * 64 + ni * 16 + frow;
            const size_t rbase = (size_t)(tileM + wm * 64 + mi * 16 + erow) * N + col;
#pragma unroll
            for (int r = 0; r < 4; ++r)
                C[rbase + (size_t)r * N] = (_Float16)acc[mi][ni][r];
        }
}

// ---------------------------------------------------------------------------
// RK4 scan, 2 barriers/stage. One block (4 waves) per batch element.
// Wave w owns G rows m = w*32..w*32+31 (col d = lane). z-index j0 = w*32+(lane&31)
// computed redundantly by lane pairs; broadcast to G-matvec via v_readlane
// (no LDS). Race-freedom of the 2-barrier schedule: waves 1-3 write part(st+1)
// only after barrier-1(st+1), which wave 0 passes only after reading part(st).
// ---------------------------------------------------------------------------
__global__ __launch_bounds__(256) void ode_chunk(const _Float16* __restrict__ G,
                                                 const float* __restrict__ W1,
                                                 const float* __restrict__ b1,
                                                 float* __restrict__ h_state) {
    const int b = blockIdx.x, t = threadIdx.x;
    const int lane = t & 63, w = t >> 6;
    const int j0 = w * 32 + (lane & 31);       // this thread's z index
    __shared__ float ys[D_SZ];
    __shared__ float part[4][D_SZ];

    float w1c[D_SZ];                           // W1[:, j0]
#pragma unroll
    for (int dd = 0; dd < D_SZ; ++dd) w1c[dd] = W1[dd * MLP_SZ + j0];
    const float b1v = b1[j0];

    float hsv = 0.0f;
    float k_st[4] = {0.f, 0.f, 0.f, 0.f};
    if (w == 0) hsv = h_state[b * H_SZ + lane];

    _Float16 praw[32];
    _Float16 b2pre = (_Float16)0.0f;
    {
        const _Float16* Gr = G + (size_t)b * NCOLS;   // s = 0
#pragma unroll
        for (int q = 0; q < 32; ++q) praw[q] = Gr[(w * 32 + q) * 64 + lane];
        if (w == 0) b2pre = Gr[8192 + lane];
    }

#pragma unroll 1
    for (int s = 0; s < NC; ++s) {
        float gcur[32];
#pragma unroll
        for (int q = 0; q < 32; ++q) gcur[q] = (float)praw[q];
        const float b2cur = (float)b2pre;
        if (s + 1 < NC) {                      // prefetch next step (hidden by stages)
            const _Float16* Gr = G + (size_t)((s + 1) * B_SZ + b) * NCOLS;
#pragma unroll
            for (int q = 0; q < 32; ++q) praw[q] = Gr[(w * 32 + q) * 64 + lane];
            if (w == 0) b2pre = Gr[8192 + lane];
        }

#pragma unroll
        for (int st = 0; st < 4; ++st) {
            if (w == 0) {
                float y = hsv;
                if (st == 1) y += 0.5f * k_st[0];
                else if (st == 2) y += 0.5f * k_st[1];
                else if (st == 3) y += k_st[2];
                ys[lane] = y;
            }
            __syncthreads();                   // barrier 1: ys visible
            float a = 0.0f;
#pragma unroll
            for (int dd = 0; dd < D_SZ; dd += 4) {
                const float4 yv = *(const float4*)&ys[dd];   // broadcast reads
                a += yv.x * w1c[dd] + yv.y * w1c[dd + 1]
                   + yv.z * w1c[dd + 2] + yv.w * w1c[dd + 3];
            }
            const float x = b1v + a;
            const float ex = __expf(2.0f * x);               // tanh(x)=1-2/(e^2x+1)
            const float z = 1.0f - 2.0f / (ex + 1.0f);
            float a2 = 0.0f;
#pragma unroll
            for (int q = 0; q < 32; ++q)
                a2 += gcur[q] * rlane(z, q);                 // z[w*32+q] from lane q
            part[w][lane] = a2;
            __syncthreads();                   // barrier 2: part visible
            if (w == 0)
                k_st[st] = b2cur + part[0][lane] + part[1][lane]
                         + part[2][lane] + part[3][lane];
        }
        if (w == 0)
            hsv += (k_st[0] + 2.0f * k_st[1] + 2.0f * k_st[2] + k_st[3]) * (1.0f / 6.0f);
    }
    if (w == 0) h_state[b * H_SZ + lane] = hsv;
}

// ---------------------------------------------------------------------------
// out = hT @ W_out + b_out             <<<256, 64>>>
// ---------------------------------------------------------------------------
__global__ void out_kernel(const float* __restrict__ h_state, const float* __restrict__ W_out,
                           const float* __restrict__ b_out, float* __restrict__ out) {
    const int b = blockIdx.x, t = threadIdx.x;
    __shared__ float hh[H_SZ];
    hh[t] = h_state[b * H_SZ + t];
    __syncthreads();
    if (t < OUT_SZ) {
        float acc = b_out[t];
        for (int d = 0; d < H_SZ; ++d) acc += hh[d] * W_out[d * OUT_SZ + t];
        out[b * OUT_SZ + t] = acc;
    }
}

extern "C" void kernel_launch(void* const* d_in, const int* in_sizes, int n_in,
                              void* d_out, int out_size, void* d_ws, size_t ws_size,
                              hipStream_t stream) {
    (void)in_sizes; (void)n_in; (void)out_size; (void)ws_size;
    const float* X     = (const float*)d_in[0];
    const float* W_in  = (const float*)d_in[1];
    const float* b_in  = (const float*)d_in[2];
    const float* W1    = (const float*)d_in[3];
    const float* b1    = (const float*)d_in[4];
    const float* W2    = (const float*)d_in[5];
    const float* b2    = (const float*)d_in[6];
    const float* W_out = (const float*)d_in[7];
    const float* b_out = (const float*)d_in[8];
    float* out = (float*)d_out;

    // workspace layout (~120 MB total)
    char* ws = (char*)d_ws;
    size_t off = 0;
    auto take = [&](size_t bytes) { void* p = ws + off; off = (off + bytes + 255) & ~(size_t)255; return p; };
    _Float16* Bmat = (_Float16*)take((size_t)NCOLS * KDIM * 2);   // 34.6 MB
    _Float16* LSc  = (_Float16*)take((size_t)MROWS * KDIM * 2);   // 17.0 MB
    _Float16* G    = (_Float16*)take((size_t)MROWS * NCOLS * 2);  // 68.1 MB
    float*    hst  = (float*)take((size_t)B_SZ * H_SZ * 4);       // 64 KB

    build_B<<<8192, 256, 0, stream>>>(W2, b2, Bmat);
    h0_kernel<<<B_SZ, H_SZ, 0, stream>>>(X, W_in, b_in, hst);

    for (int c = 0; c < NCHUNK; ++c) {
        logsig_kernel<<<dim3(B_SZ, NC), 256, 0, stream>>>(X, LSc, c * NC);
        gemm_bt<<<dim3(MROWS / 128, NCOLS / 128), 256, 0, stream>>>(
            (const unsigned short*)LSc, (const unsigned short*)Bmat, G);
        ode_chunk<<<B_SZ, 256, 0, stream>>>(G, W1, b1, hst);
    }
    out_kernel<<<B_SZ, H_SZ, 0, stream>>>(hst, W_out, b_out, out);
}

// Round 5
// 2301.714 us; speedup vs baseline: 1.4337x; 1.0309x over previous
//
#include <hip/hip_runtime.h>
#include <hip/hip_bf16.h>
#include <cstdint>
#include <cstddef>

// Problem constants
#define B_SZ   256
#define T_SZ   2049
#define D_SZ   64
#define H_SZ   64
#define MLP_SZ 128
#define NI_SZ  128
#define SEG    16          // (T-1)/NI
#define L_SZ   2080        // D + D(D-1)/2
#define NPAIR  2016
#define OUT_SZ 10

// GEMM shapes
#define NC     32                  // intervals per chunk
#define NCHUNK (NI_SZ / NC)        // 4
#define MROWS  (NC * B_SZ)         // 8192 rows per chunk GEMM
#define NCOLS  8320                // 8192 (cols n = d*128+m) + 64 (b2) + 64 zero pad
#define KDIM   L_SZ                // 2080 = 65*32

typedef _Float16 f16x8 __attribute__((ext_vector_type(8)));
typedef float    f32x4 __attribute__((ext_vector_type(4)));

__device__ __forceinline__ float rlane(float v, int l) {
    return __uint_as_float(__builtin_amdgcn_readlane(__float_as_uint(v), l));
}

// ---------------------------------------------------------------------------
// Build Bmat (fp16, [NCOLS x KDIM] row-major), PERMUTED columns-of-G order:
//   row r' = d*128 + m  (d<64, m<128) holds W2[m][d*L + l]  (l = 0..K-1)
//   rows 8192..8255: b2 row d = r'-8192  ->  b2[d*L + l]
//   rows 8256..8319: zeros
// One block per row; coalesced along l.
// ---------------------------------------------------------------------------
__global__ __launch_bounds__(256) void build_B(const float* __restrict__ W2,
                                               const float* __restrict__ b2,
                                               _Float16* __restrict__ Bm) {
    const int r = blockIdx.x, t = threadIdx.x;
    const float* src = nullptr;
    if (r < 8192) {
        const int d = r >> 7, m = r & 127;
        src = W2 + (size_t)m * (64 * KDIM) + (size_t)d * KDIM;
    } else if (r < 8256) {
        src = b2 + (size_t)(r - 8192) * KDIM;
    }
    _Float16* dst = Bm + (size_t)r * KDIM;
    for (int l = t; l < KDIM; l += 256)
        dst[l] = src ? (_Float16)src[l] : (_Float16)0.0f;
}

// ---------------------------------------------------------------------------
// h0 = X[:,0,:] @ W_in + b_in          <<<256, 64>>>
// ---------------------------------------------------------------------------
__global__ void h0_kernel(const float* __restrict__ X, const float* __restrict__ W_in,
                          const float* __restrict__ b_in, float* __restrict__ h_state) {
    const int b = blockIdx.x, t = threadIdx.x;
    __shared__ float x0[D_SZ];
    if (t < D_SZ) x0[t] = X[(size_t)b * T_SZ * D_SZ + t];
    __syncthreads();
    float acc = b_in[t];
    for (int k = 0; k < D_SZ; ++k) acc += x0[k] * W_in[k * H_SZ + t];
    h_state[b * H_SZ + t] = acc;
}

// ---------------------------------------------------------------------------
// Depth-2 log-signature, tile-structured (4x4 register tiles, Lyndon order).
// grid (256, NC), 256 threads.
// ---------------------------------------------------------------------------
__global__ __launch_bounds__(256) void logsig_kernel(const float* __restrict__ X,
                                                     _Float16* __restrict__ LS,
                                                     int n0) {
    const int b = blockIdx.x, sl = blockIdx.y, t = threadIdx.x;
    const int n = n0 + sl;
    __shared__ float seg[SEG + 1][D_SZ];
    __shared__ float cum[SEG][D_SZ];
    __shared__ float dlt[SEG][D_SZ];
    __shared__ float Mm[D_SZ][D_SZ + 1];   // +1 pad: transpose reads conflict-free

    const float* Xp = X + ((size_t)b * T_SZ + (size_t)n * SEG) * D_SZ;
    for (int i = t; i < (SEG + 1) * D_SZ / 4; i += 256)
        ((float4*)&seg[0][0])[i] = ((const float4*)Xp)[i];
    __syncthreads();
    for (int i = t; i < SEG * D_SZ; i += 256) {
        const int k = i >> 6, d = i & 63;
        cum[k][d] = seg[k][d] - seg[0][d];
        dlt[k][d] = seg[k + 1][d] - seg[k][d];
    }
    __syncthreads();

    const int ti = t >> 4, tj = t & 15;
    const int i0 = ti * 4, j0 = tj * 4;
    float m4[4][4] = {};
#pragma unroll
    for (int k = 0; k < SEG; ++k) {
        const float4 ci = *(const float4*)&cum[k][i0];
        const float4 dj = *(const float4*)&dlt[k][j0];
        const float* cip = (const float*)&ci;
        const float* djp = (const float*)&dj;
#pragma unroll
        for (int a = 0; a < 4; ++a)
#pragma unroll
            for (int c = 0; c < 4; ++c)
                m4[a][c] += cip[a] * djp[c];
    }
#pragma unroll
    for (int a = 0; a < 4; ++a)
#pragma unroll
        for (int c = 0; c < 4; ++c)
            Mm[i0 + a][j0 + c] = m4[a][c];
    __syncthreads();

    _Float16* out = LS + (size_t)(sl * B_SZ + b) * KDIM;
    if (t < D_SZ) out[t] = (_Float16)(seg[SEG][t] - seg[0][t]);   // level-1 inc
    if (tj >= ti) {
#pragma unroll
        for (int a = 0; a < 4; ++a) {
            const int i = i0 + a;
#pragma unroll
            for (int c = 0; c < 4; ++c) {
                const int j = j0 + c;
                if (j > i) {
                    const int p = 63 * i - (i * (i - 1)) / 2 + (j - i - 1);
                    out[D_SZ + p] = (_Float16)(0.5f * (m4[a][c] - Mm[j][i]));
                }
            }
        }
    }
}

// ---------------------------------------------------------------------------
// GEMM (m97 structure): C[M,N] fp16 = A[M,K] fp16 x B[N,K]^T fp16.
// 128x128 tile; BK=32; global_load_lds 16B staging; mfma_f32_16x16x32_f16.
// M=8192, N=8320, K=2080 -> grid (64, 65).
// ---------------------------------------------------------------------------
__global__ __launch_bounds__(256) void gemm_bt(const unsigned short* __restrict__ A,
                                               const unsigned short* __restrict__ Bm,
                                               _Float16* __restrict__ C) {
    constexpr int K = KDIM, N = NCOLS;
    __shared__ unsigned short As[128 * 32];
    __shared__ unsigned short Bs[128 * 32];
    const int t = threadIdx.x;
    const int lane = t & 63;
    const int w = t >> 6;
    const int wm = w & 1, wn = w >> 1;
    const int tileM = blockIdx.x * 128;
    const int tileN = blockIdx.y * 128;

    const int c0 = w * 2, c1 = c0 + 1;
    const int rs0 = c0 * 16 + (lane >> 2);
    const int rs1 = c1 * 16 + (lane >> 2);
    const int kc = (lane & 3) * 8;

    const unsigned short* gA0 = A + (size_t)(tileM + rs0) * K + kc;
    const unsigned short* gA1 = A + (size_t)(tileM + rs1) * K + kc;
    const unsigned short* gB0 = Bm + (size_t)(tileN + rs0) * K + kc;
    const unsigned short* gB1 = Bm + (size_t)(tileN + rs1) * K + kc;
    unsigned short* lA0 = As + c0 * 512 + lane * 8;
    unsigned short* lA1 = As + c1 * 512 + lane * 8;
    unsigned short* lB0 = Bs + c0 * 512 + lane * 8;
    unsigned short* lB1 = Bs + c1 * 512 + lane * 8;

    f32x4 acc[4][4] = {};
    const int frow = lane & 15;
    const int fk = (lane >> 4) * 8;

    for (int k0 = 0; k0 < K; k0 += 32) {
        __syncthreads();
        __builtin_amdgcn_global_load_lds((__attribute__((address_space(1))) void*)(gA0 + k0),
                                         (__attribute__((address_space(3))) void*)lA0, 16, 0, 0);
        __builtin_amdgcn_global_load_lds((__attribute__((address_space(1))) void*)(gA1 + k0),
                                         (__attribute__((address_space(3))) void*)lA1, 16, 0, 0);
        __builtin_amdgcn_global_load_lds((__attribute__((address_space(1))) void*)(gB0 + k0),
                                         (__attribute__((address_space(3))) void*)lB0, 16, 0, 0);
        __builtin_amdgcn_global_load_lds((__attribute__((address_space(1))) void*)(gB1 + k0),
                                         (__attribute__((address_space(3))) void*)lB1, 16, 0, 0);
        __syncthreads();

        f16x8 af[4], bfm[4];
#pragma unroll
        for (int mi = 0; mi < 4; ++mi)
            af[mi] = *(const f16x8*)(As + (wm * 64 + mi * 16 + frow) * 32 + fk);
#pragma unroll
        for (int ni = 0; ni < 4; ++ni)
            bfm[ni] = *(const f16x8*)(Bs + (wn * 64 + ni * 16 + frow) * 32 + fk);
#pragma unroll
        for (int mi = 0; mi < 4; ++mi)
#pragma unroll
            for (int ni = 0; ni < 4; ++ni)
                acc[mi][ni] = __builtin_amdgcn_mfma_f32_16x16x32_f16(af[mi], bfm[ni],
                                                                     acc[mi][ni], 0, 0, 0);
    }

    // C/D layout: col = lane&15, row = (lane>>4)*4 + reg
    const int erow = (lane >> 4) * 4;
#pragma unroll
    for (int mi = 0; mi < 4; ++mi)
#pragma unroll
        for (int ni = 0; ni < 4; ++ni) {
            const int col = tileN + wn * 64 + ni * 16 + frow;
            const size_t rbase = (size_t)(tileM + wm * 64 + mi * 16 + erow) * N + col;
#pragma unroll
            for (int r = 0; r < 4; ++r)
                C[rbase + (size_t)r * N] = (_Float16)acc[mi][ni][r];
        }
}

// ---------------------------------------------------------------------------
// RK4 scan, ONE barrier per stage. One block (4 waves) per batch element.
// G column layout n = d*128 + m: thread (w, lane) reads m = w*32..w*32+31 at
// d = lane as 4 contiguous 16B vector loads. Per-wave private ysw copy (in-wave
// LDS write->read needs only lgkmcnt), double-buffered part[], all waves
// compute k redundantly (bitwise-identical -> benign).
// ---------------------------------------------------------------------------
__global__ __launch_bounds__(256) void ode_chunk(const _Float16* __restrict__ G,
                                                 const float* __restrict__ W1,
                                                 const float* __restrict__ b1,
                                                 float* __restrict__ h_state) {
    const int b = blockIdx.x, t = threadIdx.x;
    const int lane = t & 63, w = t >> 6;
    const int j0 = w * 32 + (lane & 31);       // this thread's z index
    __shared__ float ysw[4][D_SZ];             // per-wave y copies
    __shared__ float part[2][4][D_SZ];         // double-buffered partials

    float w1c[D_SZ];                           // W1[:, j0]
#pragma unroll
    for (int dd = 0; dd < D_SZ; ++dd) w1c[dd] = W1[dd * MLP_SZ + j0];
    const float b1v = b1[j0];

    float hsv = h_state[b * H_SZ + lane];      // all waves (redundant)
    ysw[w][lane] = hsv;
    float k_st[4] = {0.f, 0.f, 0.f, 0.f};

    f16x8 pr[4];
    _Float16 b2pre;
    {
        const _Float16* Gr = G + (size_t)b * NCOLS;   // s = 0
        const f16x8* gp = (const f16x8*)(Gr + lane * 128 + w * 32);
#pragma unroll
        for (int v = 0; v < 4; ++v) pr[v] = gp[v];
        b2pre = Gr[8192 + lane];
    }

#pragma unroll 1
    for (int s = 0; s < NC; ++s) {
        float gcur[32];
#pragma unroll
        for (int v = 0; v < 4; ++v)
#pragma unroll
            for (int e = 0; e < 8; ++e) gcur[v * 8 + e] = (float)pr[v][e];
        const float b2cur = (float)b2pre;
        if (s + 1 < NC) {                      // prefetch next step (hidden by stages)
            const _Float16* Gr = G + (size_t)((s + 1) * B_SZ + b) * NCOLS;
            const f16x8* gp = (const f16x8*)(Gr + lane * 128 + w * 32);
#pragma unroll
            for (int v = 0; v < 4; ++v) pr[v] = gp[v];
            b2pre = Gr[8192 + lane];
        }

#pragma unroll
        for (int st = 0; st < 4; ++st) {
            // matvec: y from own wave's LDS copy (broadcast reads, no barrier)
            float a = 0.0f;
#pragma unroll
            for (int dd = 0; dd < D_SZ; dd += 4) {
                const float4 yv = *(const float4*)&ysw[w][dd];
                a += yv.x * w1c[dd] + yv.y * w1c[dd + 1]
                   + yv.z * w1c[dd + 2] + yv.w * w1c[dd + 3];
            }
            const float x = b1v + a;
            const float ex = __expf(2.0f * x);               // tanh(x)=1-2/(e^2x+1)
            const float z = 1.0f - 2.0f / (ex + 1.0f);
            float a2 = 0.0f;
#pragma unroll
            for (int q = 0; q < 32; ++q)
                a2 += gcur[q] * rlane(z, q);                 // z[w*32+q] from lane q
            part[st & 1][w][lane] = a2;
            __syncthreads();                   // the ONE barrier per stage
            const float kv = b2cur + part[st & 1][0][lane] + part[st & 1][1][lane]
                           + part[st & 1][2][lane] + part[st & 1][3][lane];
            k_st[st] = kv;                     // every wave, identical
            if (st < 3) {
                float y = hsv;
                if (st == 0) y += 0.5f * kv;
                else if (st == 1) y += 0.5f * kv;
                else y += kv;
                ysw[w][lane] = y;              // own copy only
            }
        }
        hsv += (k_st[0] + 2.0f * k_st[1] + 2.0f * k_st[2] + k_st[3]) * (1.0f / 6.0f);
        ysw[w][lane] = hsv;                    // stage-0 y of next step
    }
    if (w == 0) h_state[b * H_SZ + lane] = hsv;
}

// ---------------------------------------------------------------------------
// out = hT @ W_out + b_out             <<<256, 64>>>
// ---------------------------------------------------------------------------
__global__ void out_kernel(const float* __restrict__ h_state, const float* __restrict__ W_out,
                           const float* __restrict__ b_out, float* __restrict__ out) {
    const int b = blockIdx.x, t = threadIdx.x;
    __shared__ float hh[H_SZ];
    hh[t] = h_state[b * H_SZ + t];
    __syncthreads();
    if (t < OUT_SZ) {
        float acc = b_out[t];
        for (int d = 0; d < H_SZ; ++d) acc += hh[d] * W_out[d * OUT_SZ + t];
        out[b * OUT_SZ + t] = acc;
    }
}

extern "C" void kernel_launch(void* const* d_in, const int* in_sizes, int n_in,
                              void* d_out, int out_size, void* d_ws, size_t ws_size,
                              hipStream_t stream) {
    (void)in_sizes; (void)n_in; (void)out_size; (void)ws_size;
    const float* X     = (const float*)d_in[0];
    const float* W_in  = (const float*)d_in[1];
    const float* b_in  = (const float*)d_in[2];
    const float* W1    = (const float*)d_in[3];
    const float* b1    = (const float*)d_in[4];
    const float* W2    = (const float*)d_in[5];
    const float* b2    = (const float*)d_in[6];
    const float* W_out = (const float*)d_in[7];
    const float* b_out = (const float*)d_in[8];
    float* out = (float*)d_out;

    // workspace layout (~206 MB total)
    char* ws = (char*)d_ws;
    size_t off = 0;
    auto take = [&](size_t bytes) { void* p = ws + off; off = (off + bytes + 255) & ~(size_t)255; return p; };
    _Float16* Bmat = (_Float16*)take((size_t)NCOLS * KDIM * 2);   // 34.6 MB
    _Float16* LSc  = (_Float16*)take((size_t)MROWS * KDIM * 2);   // 34.1 MB
    _Float16* G    = (_Float16*)take((size_t)MROWS * NCOLS * 2);  // 136.3 MB
    float*    hst  = (float*)take((size_t)B_SZ * H_SZ * 4);       // 64 KB

    build_B<<<NCOLS, 256, 0, stream>>>(W2, b2, Bmat);
    h0_kernel<<<B_SZ, H_SZ, 0, stream>>>(X, W_in, b_in, hst);

    for (int c = 0; c < NCHUNK; ++c) {
        logsig_kernel<<<dim3(B_SZ, NC), 256, 0, stream>>>(X, LSc, c * NC);
        gemm_bt<<<dim3(MROWS / 128, NCOLS / 128), 256, 0, stream>>>(
            (const unsigned short*)LSc, (const unsigned short*)Bmat, G);
        ode_chunk<<<B_SZ, 256, 0, stream>>>(G, W1, b1, hst);
    }
    out_kernel<<<B_SZ, H_SZ, 0, stream>>>(hst, W_out, b_out, out);
}

// Round 6
// 2257.137 us; speedup vs baseline: 1.4620x; 1.0197x over previous
//
#include <hip/hip_runtime.h>
#include <hip/hip_bf16.h>
#include <cstdint>
#include <cstddef>

// Problem constants
#define B_SZ   256
#define T_SZ   2049
#define D_SZ   64
#define H_SZ   64
#define MLP_SZ 128
#define NI_SZ  128
#define SEG    16          // (T-1)/NI
#define L_SZ   2080        // D + D(D-1)/2
#define NPAIR  2016
#define OUT_SZ 10

// GEMM shapes
#define NC     32                  // intervals per chunk
#define NCHUNK (NI_SZ / NC)        // 4
#define MROWS  (NC * B_SZ)         // 8192 rows per chunk GEMM
#define NCOLS  8320                // 8192 (cols n = d*128+m) + 64 (b2) + 64 zero pad
#define KDIM   L_SZ                // 2080 = 65*32

typedef _Float16 f16x8 __attribute__((ext_vector_type(8)));
typedef float    f32x4 __attribute__((ext_vector_type(4)));

__device__ __forceinline__ float rlane(float v, int l) {
    return __uint_as_float(__builtin_amdgcn_readlane(__float_as_uint(v), l));
}

// ---------------------------------------------------------------------------
// Build Bmat (fp16, [NCOLS x KDIM] row-major), PERMUTED columns-of-G order:
//   row r' = d*128 + m  (d<64, m<128) holds W2[m][d*L + l]  (l = 0..K-1)
//   rows 8192..8255: b2 row d = r'-8192  ->  b2[d*L + l]
//   rows 8256..8319: zeros
// ---------------------------------------------------------------------------
__global__ __launch_bounds__(256) void build_B(const float* __restrict__ W2,
                                               const float* __restrict__ b2,
                                               _Float16* __restrict__ Bm) {
    const int r = blockIdx.x, t = threadIdx.x;
    const float* src = nullptr;
    if (r < 8192) {
        const int d = r >> 7, m = r & 127;
        src = W2 + (size_t)m * (64 * KDIM) + (size_t)d * KDIM;
    } else if (r < 8256) {
        src = b2 + (size_t)(r - 8192) * KDIM;
    }
    _Float16* dst = Bm + (size_t)r * KDIM;
    for (int l = t; l < KDIM; l += 256)
        dst[l] = src ? (_Float16)src[l] : (_Float16)0.0f;
}

// ---------------------------------------------------------------------------
// h0 = X[:,0,:] @ W_in + b_in          <<<256, 64>>>
// ---------------------------------------------------------------------------
__global__ void h0_kernel(const float* __restrict__ X, const float* __restrict__ W_in,
                          const float* __restrict__ b_in, float* __restrict__ h_state) {
    const int b = blockIdx.x, t = threadIdx.x;
    __shared__ float x0[D_SZ];
    if (t < D_SZ) x0[t] = X[(size_t)b * T_SZ * D_SZ + t];
    __syncthreads();
    float acc = b_in[t];
    for (int k = 0; k < D_SZ; ++k) acc += x0[k] * W_in[k * H_SZ + t];
    h_state[b * H_SZ + t] = acc;
}

// ---------------------------------------------------------------------------
// Depth-2 log-signature, tile-structured (4x4 register tiles, Lyndon order).
// grid (256, NC), 256 threads.
// ---------------------------------------------------------------------------
__global__ __launch_bounds__(256) void logsig_kernel(const float* __restrict__ X,
                                                     _Float16* __restrict__ LS,
                                                     int n0) {
    const int b = blockIdx.x, sl = blockIdx.y, t = threadIdx.x;
    const int n = n0 + sl;
    __shared__ float seg[SEG + 1][D_SZ];
    __shared__ float cum[SEG][D_SZ];
    __shared__ float dlt[SEG][D_SZ];
    __shared__ float Mm[D_SZ][D_SZ + 1];   // +1 pad: transpose reads conflict-free

    const float* Xp = X + ((size_t)b * T_SZ + (size_t)n * SEG) * D_SZ;
    for (int i = t; i < (SEG + 1) * D_SZ / 4; i += 256)
        ((float4*)&seg[0][0])[i] = ((const float4*)Xp)[i];
    __syncthreads();
    for (int i = t; i < SEG * D_SZ; i += 256) {
        const int k = i >> 6, d = i & 63;
        cum[k][d] = seg[k][d] - seg[0][d];
        dlt[k][d] = seg[k + 1][d] - seg[k][d];
    }
    __syncthreads();

    const int ti = t >> 4, tj = t & 15;
    const int i0 = ti * 4, j0 = tj * 4;
    float m4[4][4] = {};
#pragma unroll
    for (int k = 0; k < SEG; ++k) {
        const float4 ci = *(const float4*)&cum[k][i0];
        const float4 dj = *(const float4*)&dlt[k][j0];
        const float* cip = (const float*)&ci;
        const float* djp = (const float*)&dj;
#pragma unroll
        for (int a = 0; a < 4; ++a)
#pragma unroll
            for (int c = 0; c < 4; ++c)
                m4[a][c] += cip[a] * djp[c];
    }
#pragma unroll
    for (int a = 0; a < 4; ++a)
#pragma unroll
        for (int c = 0; c < 4; ++c)
            Mm[i0 + a][j0 + c] = m4[a][c];
    __syncthreads();

    _Float16* out = LS + (size_t)(sl * B_SZ + b) * KDIM;
    if (t < D_SZ) out[t] = (_Float16)(seg[SEG][t] - seg[0][t]);   // level-1 inc
    if (tj >= ti) {
#pragma unroll
        for (int a = 0; a < 4; ++a) {
            const int i = i0 + a;
#pragma unroll
            for (int c = 0; c < 4; ++c) {
                const int j = j0 + c;
                if (j > i) {
                    const int p = 63 * i - (i * (i - 1)) / 2 + (j - i - 1);
                    out[D_SZ + p] = (_Float16)(0.5f * (m4[a][c] - Mm[j][i]));
                }
            }
        }
    }
}

// ---------------------------------------------------------------------------
// GEMM (m97 structure + XOR k-chunk LDS swizzle): C[M,N] fp16 = A x B^T.
// LDS slot (row, j) holds global k-chunk (j ^ (row&3)) -> 16-lane fragment
// reads spread over 8 banks at 2-way (free) instead of 2 banks at 8-way.
// 128x128 tile; BK=32; global_load_lds 16B staging; mfma_f32_16x16x32_f16.
// M=8192, N=8320, K=2080 -> grid (64, 65).
// ---------------------------------------------------------------------------
__global__ __launch_bounds__(256) void gemm_bt(const unsigned short* __restrict__ A,
                                               const unsigned short* __restrict__ Bm,
                                               _Float16* __restrict__ C) {
    constexpr int K = KDIM, N = NCOLS;
    __shared__ unsigned short As[128 * 32];
    __shared__ unsigned short Bs[128 * 32];
    const int t = threadIdx.x;
    const int lane = t & 63;
    const int w = t >> 6;
    const int wm = w & 1, wn = w >> 1;
    const int tileM = blockIdx.x * 128;
    const int tileN = blockIdx.y * 128;

    const int c0 = w * 2, c1 = c0 + 1;
    const int rs0 = c0 * 16 + (lane >> 2);
    const int rs1 = c1 * 16 + (lane >> 2);
    // swizzled source k-chunk: j ^ (row&3), row&3 == (lane>>2)&3
    const int kc = (((lane & 3) ^ ((lane >> 2) & 3))) * 8;

    const unsigned short* gA0 = A + (size_t)(tileM + rs0) * K + kc;
    const unsigned short* gA1 = A + (size_t)(tileM + rs1) * K + kc;
    const unsigned short* gB0 = Bm + (size_t)(tileN + rs0) * K + kc;
    const unsigned short* gB1 = Bm + (size_t)(tileN + rs1) * K + kc;
    unsigned short* lA0 = As + c0 * 512 + lane * 8;
    unsigned short* lA1 = As + c1 * 512 + lane * 8;
    unsigned short* lB0 = Bs + c0 * 512 + lane * 8;
    unsigned short* lB1 = Bs + c1 * 512 + lane * 8;

    f32x4 acc[4][4] = {};
    const int frow = lane & 15;
    // read-side swizzle: want k-chunk jj=(lane>>4); stored at jj ^ (row&3),
    // row&3 == frow&3 for all fragment rows (wm*64, mi*16 are mult. of 4)
    const int fkswz = (((lane >> 4) ^ (frow & 3))) * 8;

    for (int k0 = 0; k0 < K; k0 += 32) {
        __syncthreads();
        __builtin_amdgcn_global_load_lds((__attribute__((address_space(1))) void*)(gA0 + k0),
                                         (__attribute__((address_space(3))) void*)lA0, 16, 0, 0);
        __builtin_amdgcn_global_load_lds((__attribute__((address_space(1))) void*)(gA1 + k0),
                                         (__attribute__((address_space(3))) void*)lA1, 16, 0, 0);
        __builtin_amdgcn_global_load_lds((__attribute__((address_space(1))) void*)(gB0 + k0),
                                         (__attribute__((address_space(3))) void*)lB0, 16, 0, 0);
        __builtin_amdgcn_global_load_lds((__attribute__((address_space(1))) void*)(gB1 + k0),
                                         (__attribute__((address_space(3))) void*)lB1, 16, 0, 0);
        __syncthreads();

        f16x8 af[4], bfm[4];
#pragma unroll
        for (int mi = 0; mi < 4; ++mi)
            af[mi] = *(const f16x8*)(As + (wm * 64 + mi * 16 + frow) * 32 + fkswz);
#pragma unroll
        for (int ni = 0; ni < 4; ++ni)
            bfm[ni] = *(const f16x8*)(Bs + (wn * 64 + ni * 16 + frow) * 32 + fkswz);
#pragma unroll
        for (int mi = 0; mi < 4; ++mi)
#pragma unroll
            for (int ni = 0; ni < 4; ++ni)
                acc[mi][ni] = __builtin_amdgcn_mfma_f32_16x16x32_f16(af[mi], bfm[ni],
                                                                     acc[mi][ni], 0, 0, 0);
    }

    // C/D layout: col = lane&15, row = (lane>>4)*4 + reg
    const int erow = (lane >> 4) * 4;
#pragma unroll
    for (int mi = 0; mi < 4; ++mi)
#pragma unroll
        for (int ni = 0; ni < 4; ++ni) {
            const int col = tileN + wn * 64 + ni * 16 + frow;
            const size_t rbase = (size_t)(tileM + wm * 64 + mi * 16 + erow) * N + col;
#pragma unroll
            for (int r = 0; r < 4; ++r)
                C[rbase + (size_t)r * N] = (_Float16)acc[mi][ni][r];
        }
}

// ---------------------------------------------------------------------------
// RK4 scan, ONE barrier per stage. One block (4 waves) per batch element.
// G column layout n = d*128 + m: thread (w, lane) reads m = w*32..w*32+31 at
// d = lane as 4 contiguous 16B vector loads. Per-wave private ysw copy,
// double-buffered part[], all waves compute k redundantly (identical).
// ---------------------------------------------------------------------------
__global__ __launch_bounds__(256) void ode_chunk(const _Float16* __restrict__ G,
                                                 const float* __restrict__ W1,
                                                 const float* __restrict__ b1,
                                                 float* __restrict__ h_state) {
    const int b = blockIdx.x, t = threadIdx.x;
    const int lane = t & 63, w = t >> 6;
    const int j0 = w * 32 + (lane & 31);       // this thread's z index
    __shared__ float ysw[4][D_SZ];             // per-wave y copies
    __shared__ float part[2][4][D_SZ];         // double-buffered partials

    float w1c[D_SZ];                           // W1[:, j0]
#pragma unroll
    for (int dd = 0; dd < D_SZ; ++dd) w1c[dd] = W1[dd * MLP_SZ + j0];
    const float b1v = b1[j0];

    float hsv = h_state[b * H_SZ + lane];      // all waves (redundant)
    ysw[w][lane] = hsv;
    float k_st[4] = {0.f, 0.f, 0.f, 0.f};

    f16x8 pr[4];
    _Float16 b2pre;
    {
        const _Float16* Gr = G + (size_t)b * NCOLS;   // s = 0
        const f16x8* gp = (const f16x8*)(Gr + lane * 128 + w * 32);
#pragma unroll
        for (int v = 0; v < 4; ++v) pr[v] = gp[v];
        b2pre = Gr[8192 + lane];
    }

#pragma unroll 1
    for (int s = 0; s < NC; ++s) {
        float gcur[32];
#pragma unroll
        for (int v = 0; v < 4; ++v)
#pragma unroll
            for (int e = 0; e < 8; ++e) gcur[v * 8 + e] = (float)pr[v][e];
        const float b2cur = (float)b2pre;
        if (s + 1 < NC) {                      // prefetch next step (hidden by stages)
            const _Float16* Gr = G + (size_t)((s + 1) * B_SZ + b) * NCOLS;
            const f16x8* gp = (const f16x8*)(Gr + lane * 128 + w * 32);
#pragma unroll
            for (int v = 0; v < 4; ++v) pr[v] = gp[v];
            b2pre = Gr[8192 + lane];
        }

#pragma unroll
        for (int st = 0; st < 4; ++st) {
            float a = 0.0f;
#pragma unroll
            for (int dd = 0; dd < D_SZ; dd += 4) {
                const float4 yv = *(const float4*)&ysw[w][dd];
                a += yv.x * w1c[dd] + yv.y * w1c[dd + 1]
                   + yv.z * w1c[dd + 2] + yv.w * w1c[dd + 3];
            }
            const float x = b1v + a;
            const float ex = __expf(2.0f * x);               // tanh(x)=1-2/(e^2x+1)
            const float z = 1.0f - 2.0f / (ex + 1.0f);
            float a2 = 0.0f;
#pragma unroll
            for (int q = 0; q < 32; ++q)
                a2 += gcur[q] * rlane(z, q);                 // z[w*32+q] from lane q
            part[st & 1][w][lane] = a2;
            __syncthreads();                   // the ONE barrier per stage
            const float kv = b2cur + part[st & 1][0][lane] + part[st & 1][1][lane]
                           + part[st & 1][2][lane] + part[st & 1][3][lane];
            k_st[st] = kv;                     // every wave, identical
            if (st < 3) {
                float y = hsv;
                if (st == 0) y += 0.5f * kv;
                else if (st == 1) y += 0.5f * kv;
                else y += kv;
                ysw[w][lane] = y;              // own copy only
            }
        }
        hsv += (k_st[0] + 2.0f * k_st[1] + 2.0f * k_st[2] + k_st[3]) * (1.0f / 6.0f);
        ysw[w][lane] = hsv;                    // stage-0 y of next step
    }
    if (w == 0) h_state[b * H_SZ + lane] = hsv;
}

// ---------------------------------------------------------------------------
// out = hT @ W_out + b_out             <<<256, 64>>>
// ---------------------------------------------------------------------------
__global__ void out_kernel(const float* __restrict__ h_state, const float* __restrict__ W_out,
                           const float* __restrict__ b_out, float* __restrict__ out) {
    const int b = blockIdx.x, t = threadIdx.x;
    __shared__ float hh[H_SZ];
    hh[t] = h_state[b * H_SZ + t];
    __syncthreads();
    if (t < OUT_SZ) {
        float acc = b_out[t];
        for (int d = 0; d < H_SZ; ++d) acc += hh[d] * W_out[d * OUT_SZ + t];
        out[b * OUT_SZ + t] = acc;
    }
}

extern "C" void kernel_launch(void* const* d_in, const int* in_sizes, int n_in,
                              void* d_out, int out_size, void* d_ws, size_t ws_size,
                              hipStream_t stream) {
    (void)in_sizes; (void)n_in; (void)out_size; (void)ws_size;
    const float* X     = (const float*)d_in[0];
    const float* W_in  = (const float*)d_in[1];
    const float* b_in  = (const float*)d_in[2];
    const float* W1    = (const float*)d_in[3];
    const float* b1    = (const float*)d_in[4];
    const float* W2    = (const float*)d_in[5];
    const float* b2    = (const float*)d_in[6];
    const float* W_out = (const float*)d_in[7];
    const float* b_out = (const float*)d_in[8];
    float* out = (float*)d_out;

    // workspace layout (~206 MB total)
    char* ws = (char*)d_ws;
    size_t off = 0;
    auto take = [&](size_t bytes) { void* p = ws + off; off = (off + bytes + 255) & ~(size_t)255; return p; };
    _Float16* Bmat = (_Float16*)take((size_t)NCOLS * KDIM * 2);   // 34.6 MB
    _Float16* LSc  = (_Float16*)take((size_t)MROWS * KDIM * 2);   // 34.1 MB
    _Float16* G    = (_Float16*)take((size_t)MROWS * NCOLS * 2);  // 136.3 MB
    float*    hst  = (float*)take((size_t)B_SZ * H_SZ * 4);       // 64 KB

    build_B<<<NCOLS, 256, 0, stream>>>(W2, b2, Bmat);
    h0_kernel<<<B_SZ, H_SZ, 0, stream>>>(X, W_in, b_in, hst);

    for (int c = 0; c < NCHUNK; ++c) {
        logsig_kernel<<<dim3(B_SZ, NC), 256, 0, stream>>>(X, LSc, c * NC);
        gemm_bt<<<dim3(MROWS / 128, NCOLS / 128), 256, 0, stream>>>(
            (const unsigned short*)LSc, (const unsigned short*)Bmat, G);
        ode_chunk<<<B_SZ, 256, 0, stream>>>(G, W1, b1, hst);
    }
    out_kernel<<<B_SZ, H_SZ, 0, stream>>>(hst, W_out, b_out, out);
}